// Round 12
// baseline (383.629 us; speedup 1.0000x reference)
//
#include <hip/hip_runtime.h>

typedef unsigned short u16;
typedef unsigned int   u32;
typedef __bf16 bf16x8 __attribute__((ext_vector_type(8)));
typedef float  f32x16 __attribute__((ext_vector_type(16)));

__device__ __forceinline__ u16 f2bf(float f){
  u32 u = __float_as_uint(f);
  u32 r = (u + 0x7FFFu + ((u >> 16) & 1u)) >> 16;   // RNE
  return (u16)r;
}

// Counted wait (never 0 in the main loop) + rule-18 fence.
#define WAITV(N) do { \
    asm volatile("s_waitcnt vmcnt(" N ")"); \
    __builtin_amdgcn_sched_barrier(0); \
  } while (0)
// Raw barrier with memory clobber: orders C-level LDS reads across it
// WITHOUT the compiler's vmcnt(0) drain (the m97/R11 ~90us stall).
#define BAR() asm volatile("s_barrier" ::: "memory")

// ===========================================================================
// TILED OPERAND LAYOUT (validated R8: 735->397us):
// tile = 32 rows x 16 k = 1KB; elem (row,k) -> tile (row>>5, k>>4),
// lane = (row&31)|(((k>>3)&1)<<5), byte = tile*1024 + lane*16 + (k&7)*2.
// One tile = ONE contiguous 1KB block in exact lane order -> perfect
// global_load_lds source (linear dest) AND conflict-free ds_read_b128.
//
// R11 post-mortem: __syncthreads drains vmcnt(0) every chunk (m97 stall).
// R12: counted-vmcnt 4-buffer pipeline (T3+T4) -- loads stay in flight
// across raw s_barriers; vmcnt(12) waits only the chunk being consumed.
// ===========================================================================

// ---------------------------------------------------------------------------
// Pass 1: row sums + f32->bf16 + transpose to tiled layout via LDS.
// ---------------------------------------------------------------------------
__global__ __launch_bounds__(1024) void rowsum_tileA(
    const float* __restrict__ A, u16* __restrict__ Ab, float* __restrict__ ds){
  __shared__ u16 lt[8192];               // 16 tiles x 512 u16 = 16 KB
  const int t = threadIdx.x;
  const int r = t >> 5, q = t & 31;      // row 0..31, 32 threads/row
  const int rg = blockIdx.x;
  const float* ar = A + ((size_t)rg * 32 + r) * 8192;
  float s = 0.f;
  for (int ch = 0; ch < 32; ++ch){
    #pragma unroll
    for (int j = 0; j < 2; ++j){
      const int c4 = ch * 64 + j * 32 + q;           // float4 col index
      float4 v = ((const float4*)ar)[c4];
      s += (v.x + v.y) + (v.z + v.w);
      const int cl = (j * 32 + q) * 4;               // local col 0..255
      const int idx = (cl >> 4) * 512 + ((r | (((cl >> 3) & 1) << 5)) * 8) + (cl & 7);
      ushort4 o;
      o.x = f2bf(v.x); o.y = f2bf(v.y); o.z = f2bf(v.z); o.w = f2bf(v.w);
      *(ushort4*)(lt + idx) = o;
    }
    __syncthreads();
    uint4* dst = (uint4*)(Ab + ((size_t)rg * 512 + ch * 16) * 512);
    dst[t] = ((const uint4*)lt)[t];                  // linear 16KB, coalesced
    __syncthreads();
  }
  #pragma unroll
  for (int m = 16; m > 0; m >>= 1) s += __shfl_xor(s, m, 64);
  if (q == 0) ds[rg * 32 + r] = rsqrtf(s);
}

// ---------------------------------------------------------------------------
// Small feature GEMM: Vt tiles = bf16( ds[i] * sum_k in[i][k] * W[k][o] )
// Output in tiled layout.
// ---------------------------------------------------------------------------
template<int K, int F, bool INBF16>
__global__ __launch_bounds__(256) void small_gemm(
    const void* __restrict__ inp, const float* __restrict__ W,
    const float* __restrict__ ds, u16* __restrict__ Vt){
  constexpr int G   = 256 / F;     // 1 (F=256) or 2 (F=128)
  constexpr int RPB = 16 * G;      // rows per block
  __shared__ float xs[RPB * K];
  const int t  = threadIdx.x;
  const int r0 = blockIdx.x * RPB;
  if constexpr (INBF16){
    const u16* ip = (const u16*)inp + (size_t)r0 * K;
    constexpr int IT = (RPB * K) / (256 * 8);
    #pragma unroll
    for (int j = 0; j < IT; ++j){
      int c = j * 256 + t;
      uint4 v = ((const uint4*)ip)[c];
      float* xp = xs + c * 8;
      xp[0] = __uint_as_float((v.x & 0xFFFFu) << 16);
      xp[1] = __uint_as_float(v.x & 0xFFFF0000u);
      xp[2] = __uint_as_float((v.y & 0xFFFFu) << 16);
      xp[3] = __uint_as_float(v.y & 0xFFFF0000u);
      xp[4] = __uint_as_float((v.z & 0xFFFFu) << 16);
      xp[5] = __uint_as_float(v.z & 0xFFFF0000u);
      xp[6] = __uint_as_float((v.w & 0xFFFFu) << 16);
      xp[7] = __uint_as_float(v.w & 0xFFFF0000u);
    }
  } else {
    const float* ip = (const float*)inp + (size_t)r0 * K;
    constexpr int IT = (RPB * K) / (256 * 4);
    #pragma unroll
    for (int j = 0; j < IT; ++j){
      int c = j * 256 + t;
      ((float4*)xs)[c] = ((const float4*)ip)[c];
    }
  }
  __syncthreads();
  const int o = t % F, g = t / F;
  float acc[16];
  #pragma unroll
  for (int r = 0; r < 16; ++r) acc[r] = 0.f;
  const float* xr = xs + g * 16 * K;
  for (int k = 0; k < K; k += 4){
    float w0 = W[(k+0)*F + o];
    float w1 = W[(k+1)*F + o];
    float w2 = W[(k+2)*F + o];
    float w3 = W[(k+3)*F + o];
    #pragma unroll
    for (int r = 0; r < 16; ++r){
      float4 xv = *(const float4*)(xr + r*K + k);
      acc[r] += xv.x*w0 + xv.y*w1 + xv.z*w2 + xv.w*w3;
    }
  }
  const int rb = r0 + g * 16;              // 16-aligned -> one k-tile
  union { u16 u[16]; uint4 v[2]; } pk;
  #pragma unroll
  for (int r = 0; r < 16; ++r) pk.u[r] = f2bf(acc[r] * ds[rb + r]);
  const size_t tile = ((size_t)(o >> 5) * 512 + (rb >> 4)) * 512;
  uint4* dst = (uint4*)(Vt + tile + (size_t)(o & 31) * 8);
  dst[0]  = pk.v[0];
  dst[32] = pk.v[1];
}

// ---------------------------------------------------------------------------
// Big GEMM, counted-vmcnt LDS pipeline (T3+T4 applied to the R11 structure).
// out[i][o] = ds[i]*sum_j Ab[i][j]*Vt[o][j]  (+relu / f32-out variants)
//
// Block = 64 rows x 64 cols, 256 thr / 4 waves (2x2 quadrants of 32x32).
// K-chunks of 64 (16 tiles = 16KB); 4 LDS buffers (64KB); prefetch depth 3.
// Per iter/wave: stage(c+3)=4 global_load_lds -> vmcnt(12) [stage(c) done,
// 12 loads REMAIN IN FLIGHT across the barrier] -> s_barrier -> 8 ds_read
// + 4 MFMA -> sched_barrier(0)+s_barrier. No vmcnt(0) until the tail.
// Grid = 128*CG; rowg = bid&127 (A-sharing blocks land on the same XCD).
// ---------------------------------------------------------------------------
template<int CG, bool RELU, bool OUTF32>
__global__ __launch_bounds__(256) void gemm_cnt(
    const u16* __restrict__ Ab, const u16* __restrict__ Vt,
    const float* __restrict__ ds, u16* __restrict__ Hout, float* __restrict__ Fout){
  constexpr int F = CG * 64;
  __shared__ u16 Ls[4][16 * 512];        // 4 buffers x 16 KB
  const int t = threadIdx.x, w = t >> 6, lane = t & 63;
  const int wr = w >> 1, wc = w & 1;
  const int rowg = blockIdx.x & 127;
  const int colg = blockIdx.x >> 7;      // 0..CG-1

  // wave w stages panel w: 0,1 = A row-tiles; 2,3 = B col-tiles.
  const u16* src = (w < 2)
    ? Ab + ((size_t)(rowg * 2 + w)        * 512) * 512 + lane * 8
    : Vt + ((size_t)(colg * 2 + (w - 2)) * 512) * 512 + lane * 8;

  f32x16 acc;
  #pragma unroll
  for (int i = 0; i < 16; ++i) acc[i] = 0.f;

  auto stage = [&](int ck){
    u16* L = &Ls[ck & 3][w * 4 * 512] + lane * 8;
    const u16* s = src + (size_t)ck * 4 * 512;
    #pragma unroll
    for (int kt = 0; kt < 4; ++kt){
      __builtin_amdgcn_global_load_lds(
        (const __attribute__((address_space(1))) u32*)(s + kt * 512),
        (__attribute__((address_space(3))) u32*)(L + kt * 512), 16, 0, 0);
    }
  };
  auto compute = [&](int ck){
    const u16* La = &Ls[ck & 3][(wr * 4) * 512] + lane * 8;
    const u16* Lb = &Ls[ck & 3][(8 + wc * 4) * 512] + lane * 8;
    #pragma unroll
    for (int kt = 0; kt < 4; ++kt){
      bf16x8 a = *(const bf16x8*)(const void*)(La + kt * 512);
      bf16x8 b = *(const bf16x8*)(const void*)(Lb + kt * 512);
      acc = __builtin_amdgcn_mfma_f32_32x32x16_bf16(a, b, acc, 0, 0, 0);
    }
  };

  stage(0); stage(1); stage(2);          // 12 loads in flight
  for (int c = 0; c < 125; ++c){
    stage(c + 3);                        // -> 16 in flight
    WAITV("12");                         // stage(c) landed; 12 stay in flight
    BAR();
    compute(c);
    __builtin_amdgcn_sched_barrier(0);   // pin MFMAs+waits above the barrier
    BAR();
  }
  WAITV("8");  BAR(); compute(125); __builtin_amdgcn_sched_barrier(0); BAR();
  WAITV("4");  BAR(); compute(126); __builtin_amdgcn_sched_barrier(0); BAR();
  WAITV("0");  BAR(); compute(127);

  // epilogue (C/D layout m74/m101): col = lane&31, row = (r&3)+8*(r>>2)+4*(lane>>5)
  const int rhi = (lane >> 5) << 2;
  const int cl  = lane & 31;
  const int rbase = rowg * 64 + wr * 32;
  const int cbase = colg * 64 + wc * 32;
  #pragma unroll
  for (int r = 0; r < 16; ++r){
    const int rl = (r & 3) + ((r >> 2) << 3) + rhi;
    const int row = rbase + rl;
    float v = acc[r] * ds[row];
    if (RELU) v = fmaxf(v, 0.f);
    if (OUTF32) Fout[(size_t)row * F + cbase + cl] = v;
    else        Hout[(size_t)row * F + cbase + cl] = f2bf(v);
  }
}

// ---------------------------------------------------------------------------
// Attention scores: sc[i] = tanh(Z[i,:] @ Wl^T + bl) @ q + b
// ---------------------------------------------------------------------------
__device__ __forceinline__ float tanh_fast(float x){
  x = fminf(fmaxf(x, -15.f), 15.f);
  float e = __expf(2.f * x);
  return (e - 1.f) / (e + 1.f);
}

__global__ __launch_bounds__(256) void attn_scores(
    const float* __restrict__ Z, const float* __restrict__ Wl,
    const float* __restrict__ bl, const float* __restrict__ q,
    const float* __restrict__ bsc, float* __restrict__ sc){
  __shared__ float wl[128 * 128];          // 64 KiB exactly, swizzled
  const int t = threadIdx.x, lane = t & 63, wave = t >> 6;
  for (int j = 0; j < 64; ++j){
    int idx = j * 256 + t;
    int o = idx >> 7, k = idx & 127;
    int c = k >> 2, e = k & 3;
    wl[o * 128 + (((c ^ (o & 31)) << 2) | e)] = Wl[idx];
  }
  __syncthreads();
  const float bl0 = bl[lane], bl1 = bl[lane + 64];
  const float q0  = q[lane],  q1  = q[lane + 64];
  const float bb  = bsc[0];
  const int r0 = blockIdx.x * 16;
  for (int rr = 0; rr < 4; ++rr){
    int r = r0 + wave * 4 + rr;
    float d0 = 0.f, d1 = 0.f;
    #pragma unroll
    for (int c = 0; c < 32; ++c){
      float4 zv = *(const float4*)(Z + (size_t)r * 128 + c * 4);
      float4 w0 = *(const float4*)&wl[ lane      * 128 + ((c ^ (lane & 31)) << 2)];
      float4 w1 = *(const float4*)&wl[(lane + 64)* 128 + ((c ^ (lane & 31)) << 2)];
      d0 += zv.x*w0.x + zv.y*w0.y + zv.z*w0.z + zv.w*w0.w;
      d1 += zv.x*w1.x + zv.y*w1.y + zv.z*w1.z + zv.w*w1.w;
    }
    float s = tanh_fast(d0 + bl0) * q0 + tanh_fast(d1 + bl1) * q1;
    #pragma unroll
    for (int off = 32; off > 0; off >>= 1) s += __shfl_down(s, off, 64);
    if (lane == 0) sc[r] = s + bb;
  }
}

__global__ __launch_bounds__(1024) void softmax_red(
    const float* __restrict__ sc, float* __restrict__ sred){
  const int t = threadIdx.x, lane = t & 63, wave = t >> 6;
  __shared__ float red[16];
  float m = -1e30f;
  for (int i = t; i < 8192; i += 1024) m = fmaxf(m, sc[i]);
  #pragma unroll
  for (int off = 32; off > 0; off >>= 1) m = fmaxf(m, __shfl_down(m, off, 64));
  if (lane == 0) red[wave] = m;
  __syncthreads();
  if (t == 0){
    float mm = red[0];
    for (int w = 1; w < 16; ++w) mm = fmaxf(mm, red[w]);
    red[0] = mm;
  }
  __syncthreads();
  const float bmax = red[0];
  __syncthreads();
  float s = 0.f;
  for (int i = t; i < 8192; i += 1024) s += __expf(sc[i] - bmax);
  #pragma unroll
  for (int off = 32; off > 0; off >>= 1) s += __shfl_down(s, off, 64);
  if (lane == 0) red[wave] = s;
  __syncthreads();
  if (t == 0){
    float ss = 0.f;
    for (int w = 0; w < 16; ++w) ss += red[w];
    sred[0] = bmax; sred[1] = ss;
  }
}

__global__ __launch_bounds__(256) void weighted_part(
    const float* __restrict__ sc, const float* __restrict__ sred,
    const float* __restrict__ Z, float* __restrict__ part){
  const int blk = blockIdx.x, t = threadIdx.x;
  const int o = t & 127, h = t >> 7;
  const float bmax = sred[0], inv = 1.f / sred[1];
  float acc = 0.f;
  const int i0 = blk * 128;
  for (int i = i0 + h; i < i0 + 128; i += 2){
    float w = __expf(sc[i] - bmax) * inv;
    acc += w * Z[(size_t)i * 128 + o];
  }
  __shared__ float l[256];
  l[t] = acc;
  __syncthreads();
  if (h == 0) part[blk * 128 + o] = l[o] + l[o + 128];
}

__global__ __launch_bounds__(128) void final_red(
    const float* __restrict__ part, float* __restrict__ out){
  const int o = threadIdx.x;
  float s = 0.f;
  for (int b = 0; b < 64; ++b) s += part[b * 128 + o];
  out[o] = s;
}

// ---------------------------------------------------------------------------
extern "C" void kernel_launch(void* const* d_in, const int* in_sizes, int n_in,
                              void* d_out, int out_size, void* d_ws, size_t ws_size,
                              hipStream_t stream){
  const float* x  = (const float*)d_in[0];
  const float* A  = (const float*)d_in[1];
  const float* W1 = (const float*)d_in[2];
  const float* W2 = (const float*)d_in[3];
  const float* W3 = (const float*)d_in[4];
  const float* Wl = (const float*)d_in[5];
  const float* bl = (const float*)d_in[6];
  const float* q  = (const float*)d_in[7];
  const float* b  = (const float*)d_in[8];
  float* out = (float*)d_out;
  char* ws = (char*)d_ws;

  u16*   AB   = (u16*)(ws);                      // 128 MiB, tiled
  float* DS   = (float*)(ws + 134217728);        // 32 KiB
  u16*   VT   = (u16*)(ws + 134250496);          // 4 MiB, tiled
  u16*   HB   = (u16*)(ws + 138444800);          // 4 MiB [8192][256] row-major
  float* SC   = (float*)(ws + 142639104);        // 8192 f32 scores
  float* SP   = (float*)(ws + 142671872);        // 64*128 f32
  float* SRED = (float*)(ws + 142704640);        // {max, sumexp}

  rowsum_tileA<<<256, 1024, 0, stream>>>(A, AB, DS);
  // layer 1
  small_gemm<128, 256, false><<<512, 256, 0, stream>>>(x, W1, DS, VT);
  gemm_cnt<4, true, false><<<512, 256, 0, stream>>>(AB, VT, DS, HB, nullptr);
  // layer 2
  small_gemm<256, 256, true><<<512, 256, 0, stream>>>(HB, W2, DS, VT);
  gemm_cnt<4, true, false><<<512, 256, 0, stream>>>(AB, VT, DS, HB, nullptr);
  // layer 3 -> z_context f32 straight into d_out
  small_gemm<256, 128, true><<<256, 256, 0, stream>>>(HB, W3, DS, VT);
  gemm_cnt<2, false, true><<<256, 256, 0, stream>>>(AB, VT, DS, nullptr, out);
  // attention pooling
  attn_scores<<<512, 256, 0, stream>>>(out, Wl, bl, q, b, SC);
  softmax_red<<<1, 1024, 0, stream>>>(SC, SRED);
  weighted_part<<<64, 256, 0, stream>>>(SC, SRED, out, SP);
  final_red<<<1, 128, 0, stream>>>(SP, out + 8192 * 128);
}